// Round 6
// baseline (289.818 us; speedup 1.0000x reference)
//
#include <hip/hip_runtime.h>

// (B,N,D,K) = (32, 2048, 512, 256)
#define CB 32
#define CN 2048
#define CD 512
#define CK 256

typedef __bf16 bf16x8 __attribute__((ext_vector_type(8)));
typedef float  f32x4  __attribute__((ext_vector_type(4)));

__device__ __forceinline__ unsigned pk2bf(float a, float b) {   // RNE pack: 2 f32 -> bf16x2
    union { float f; unsigned u; } x, y; x.f = a; y.f = b;
    unsigned ru = x.u + 0x7fffu + ((x.u >> 16) & 1u);
    unsigned rv = y.u + 0x7fffu + ((y.u >> 16) & 1u);
    return (ru >> 16) | (rv & 0xffff0000u);
}

// ---------------- K0: vQp (blocks 0..31) + WiT (blocks 32..287) ----------------
__global__ __launch_bounds__(256) void prep_kernel(
        const float* __restrict__ vQ, const float* __restrict__ Wq,
        const float* __restrict__ bq, const float* __restrict__ Wi,
        float* __restrict__ vQp, unsigned short* __restrict__ WiT)
{
    const int tid = threadIdx.x;
    if (blockIdx.x < CB) {
        const int b = blockIdx.x;
        __shared__ float sq[CD];
        sq[tid]       = vQ[b * CD + tid];
        sq[tid + 256] = vQ[b * CD + tid + 256];
        __syncthreads();
        float acc = bq[tid];
        #pragma unroll 8
        for (int d = 0; d < CD; ++d) acc += sq[d] * Wq[d * CK + tid];
        vQp[b * CK + tid] = acc;
    } else {
        const int k = blockIdx.x - CB;
        for (int d = tid; d < CD; d += 256) {
            union { float f; unsigned u; } x; x.f = Wi[(size_t)d * CK + k];
            unsigned r = x.u + 0x7fffu + ((x.u >> 16) & 1u);
            WiT[(size_t)k * CD + d] = (unsigned short)(r >> 16);
        }
    }
}

// ---------------- K1: fused scores + softmax pieces + num ----------------
// BM=64 (grid 1024 = 4 blocks/CU), BK=64, 8 chunks. A: LDS dbuf 2x8 KB,
// xor-swizzled, reg-staged in 2 halves. B: global->register fragments
// (no LDS, no glds => cheap barrier drains). One barrier per chunk.
__global__ __launch_bounds__(256, 4) void scores_fused_kernel(
        const float* __restrict__ vI, const unsigned short* __restrict__ WiT,
        const float* __restrict__ vQp, const float* __restrict__ Wp,
        float* __restrict__ numP, float* __restrict__ Zp, float* __restrict__ mP)
{
    constexpr int BM = 64;
    __shared__ __align__(16) unsigned short sA[2][BM * 64];   // 16 KB total
    float* sf   = (float*)&sA[0][0];   // 4096 floats of epilogue scratch (aliased)
    float* sred = sf;                  // [4][64]
    float* sS   = sf + 256;            // [64]
    float* sW   = sf + 320;            // [64]
    float* sacc = sf + 1024;           // [4][512]

    const int tid  = threadIdx.x;
    const int b    = blockIdx.y;
    const int n0   = blockIdx.x * BM;
    const int wave = tid >> 6;
    const int lane = tid & 63;
    const int col  = lane & 15;
    const int quad = lane >> 4;
    const float* vIb = vI + ((size_t)b * CN + n0) * CD;

    // A staging geometry: thread covers row arow, float cols acol..acol+15
    const int arow = tid >> 2;
    const int acol = (tid & 3) * 16;
    const int ac0  = (tid & 3) * 2;          // 16B-chunk ids ac0, ac0+1
    const int sw0  = (ac0 ^ (arow & 7)) << 3;
    const int sw1  = ((ac0 + 1) ^ (arow & 7)) << 3;
    const float* aSrc = vIb + (size_t)arow * CD + acol;

    // B fragment base: lane covers WiT row (wave*64 + kt*16 + col), 16B at quad*8
    const unsigned short* wB = WiT + (size_t)(wave * 64 + col) * CD + quad * 8;

    // ---- prologue: stage sA[0](ch0), load rb(ch0) ----
    uint4 rb[4][2];
    #pragma unroll
    for (int kt = 0; kt < 4; ++kt) {
        rb[kt][0] = *reinterpret_cast<const uint4*>(wB + kt * 16 * CD);
        rb[kt][1] = *reinterpret_cast<const uint4*>(wB + kt * 16 * CD + 32);
    }
    {
        float4 a0 = *reinterpret_cast<const float4*>(aSrc);
        float4 a1 = *reinterpret_cast<const float4*>(aSrc + 4);
        float4 a2 = *reinterpret_cast<const float4*>(aSrc + 8);
        float4 a3 = *reinterpret_cast<const float4*>(aSrc + 12);
        uint4 p0, p1;
        p0.x = pk2bf(a0.x, a0.y); p0.y = pk2bf(a0.z, a0.w);
        p0.z = pk2bf(a1.x, a1.y); p0.w = pk2bf(a1.z, a1.w);
        p1.x = pk2bf(a2.x, a2.y); p1.y = pk2bf(a2.z, a2.w);
        p1.z = pk2bf(a3.x, a3.y); p1.w = pk2bf(a3.z, a3.w);
        *reinterpret_cast<uint4*>(&sA[0][arow * 64 + sw0]) = p0;
        *reinterpret_cast<uint4*>(&sA[0][arow * 64 + sw1]) = p1;
    }

    f32x4 acc[4][4];
    #pragma unroll
    for (int mt = 0; mt < 4; ++mt)
        #pragma unroll
        for (int kt = 0; kt < 4; ++kt)
            acc[mt][kt] = (f32x4){0.f, 0.f, 0.f, 0.f};

    __syncthreads();

    // ---- K loop: 8 chunks of 64 d, ONE barrier per chunk ----
    #pragma unroll
    for (int ch = 0; ch < 8; ++ch) {
        const int p = ch & 1;
        float4 a0, a1;
        // issue A(ch+1) half0 loads early
        if (ch < 7) {
            const float* s0 = aSrc + (ch + 1) * 64;
            a0 = *reinterpret_cast<const float4*>(s0);
            a1 = *reinterpret_cast<const float4*>(s0 + 4);
        }
        // s = 0
        {
            bf16x8 af[4];
            #pragma unroll
            for (int mt = 0; mt < 4; ++mt) {
                int row = mt * 16 + col;
                af[mt] = *reinterpret_cast<const bf16x8*>(
                    &sA[p][row * 64 + ((quad ^ (row & 7)) << 3)]);
            }
            #pragma unroll
            for (int mt = 0; mt < 4; ++mt)
                #pragma unroll
                for (int kt = 0; kt < 4; ++kt)
                    acc[mt][kt] = __builtin_amdgcn_mfma_f32_16x16x32_bf16(
                        af[mt], __builtin_bit_cast(bf16x8, rb[kt][0]),
                        acc[mt][kt], 0, 0, 0);
        }
        // stage A(ch+1) half0; issue half1 loads
        float4 a2, a3;
        if (ch < 7) {
            uint4 p0;
            p0.x = pk2bf(a0.x, a0.y); p0.y = pk2bf(a0.z, a0.w);
            p0.z = pk2bf(a1.x, a1.y); p0.w = pk2bf(a1.z, a1.w);
            *reinterpret_cast<uint4*>(&sA[1 - p][arow * 64 + sw0]) = p0;
            const float* s1 = aSrc + (ch + 1) * 64 + 8;
            a2 = *reinterpret_cast<const float4*>(s1);
            a3 = *reinterpret_cast<const float4*>(s1 + 4);
        }
        // s = 1
        {
            bf16x8 af[4];
            #pragma unroll
            for (int mt = 0; mt < 4; ++mt) {
                int row = mt * 16 + col;
                af[mt] = *reinterpret_cast<const bf16x8*>(
                    &sA[p][row * 64 + (((4 + quad) ^ (row & 7)) << 3)]);
            }
            #pragma unroll
            for (int mt = 0; mt < 4; ++mt)
                #pragma unroll
                for (int kt = 0; kt < 4; ++kt)
                    acc[mt][kt] = __builtin_amdgcn_mfma_f32_16x16x32_bf16(
                        af[mt], __builtin_bit_cast(bf16x8, rb[kt][1]),
                        acc[mt][kt], 0, 0, 0);
        }
        if (ch < 7) {
            // load rb(ch+1): after last use of rb(ch)
            const int d0n = (ch + 1) * 64;
            #pragma unroll
            for (int kt = 0; kt < 4; ++kt) {
                rb[kt][0] = *reinterpret_cast<const uint4*>(wB + kt * 16 * CD + d0n);
                rb[kt][1] = *reinterpret_cast<const uint4*>(wB + kt * 16 * CD + d0n + 32);
            }
            // stage A(ch+1) half1
            uint4 p1;
            p1.x = pk2bf(a2.x, a2.y); p1.y = pk2bf(a2.z, a2.w);
            p1.z = pk2bf(a3.x, a3.y); p1.w = pk2bf(a3.z, a3.w);
            *reinterpret_cast<uint4*>(&sA[1 - p][arow * 64 + sw1]) = p1;
        }
        __syncthreads();
    }

    // ---- epilogue 1: per-row scores ----
    float vq[4], wp[4];
    #pragma unroll
    for (int kt = 0; kt < 4; ++kt) {
        int k = wave * 64 + kt * 16 + col;
        vq[kt] = vQp[b * CK + k];
        wp[kt] = Wp[k];
    }
    float sp[4][4];
    #pragma unroll
    for (int mt = 0; mt < 4; ++mt)
        #pragma unroll
        for (int r = 0; r < 4; ++r) {
            float s = 0.f;
            #pragma unroll
            for (int kt = 0; kt < 4; ++kt) {
                float v = acc[mt][kt][r] + vq[kt];
                v = v > 0.f ? v : 0.01f * v;     // leaky relu
                s += v * wp[kt];
            }
            sp[mt][r] = s;
        }
    #pragma unroll
    for (int off = 1; off < 16; off <<= 1)
        #pragma unroll
        for (int mt = 0; mt < 4; ++mt)
            #pragma unroll
            for (int r = 0; r < 4; ++r)
                sp[mt][r] += __shfl_xor(sp[mt][r], off);

    __syncthreads();   // last sA reads done -> safe to alias scratch
    if (col == 0) {
        #pragma unroll
        for (int mt = 0; mt < 4; ++mt)
            #pragma unroll
            for (int r = 0; r < 4; ++r)
                sred[wave * 64 + mt * 16 + quad * 4 + r] = sp[mt][r];
    }
    __syncthreads();
    if (tid < BM)
        sS[tid] = sred[tid] + sred[64 + tid] + sred[128 + tid] + sred[192 + tid];
    __syncthreads();

    // ---- epilogue 2: block-local softmax pieces ----
    float m = -1e30f;
    #pragma unroll 8
    for (int i = 0; i < BM; ++i) m = fmaxf(m, sS[i]);
    if (tid < BM) sW[tid] = __expf(sS[tid] - m);
    __syncthreads();
    const int pidx = b * 32 + blockIdx.x;
    if (tid < 64) {
        float z = sW[tid];
        #pragma unroll
        for (int off = 32; off > 0; off >>= 1) z += __shfl_xor(z, off);
        if (tid == 0) { Zp[pidx] = z; mP[pidx] = m; }
    }

    // ---- epilogue 3: num[d] = sum_n w_n * vI[n][d] (fp32, L2/L3-hot re-read) ----
    float a8[8] = {0.f, 0.f, 0.f, 0.f, 0.f, 0.f, 0.f, 0.f};
    const float* vrow = vIb + (size_t)(wave * 16) * CD + lane * 8;
    #pragma unroll 4
    for (int i = 0; i < 16; ++i) {
        float w = sW[wave * 16 + i];
        float4 u0 = *reinterpret_cast<const float4*>(vrow);
        float4 u1 = *reinterpret_cast<const float4*>(vrow + 4);
        a8[0] += w * u0.x; a8[1] += w * u0.y; a8[2] += w * u0.z; a8[3] += w * u0.w;
        a8[4] += w * u1.x; a8[5] += w * u1.y; a8[6] += w * u1.z; a8[7] += w * u1.w;
        vrow += CD;
    }
    *reinterpret_cast<float4*>(&sacc[wave * 512 + lane * 8])     = (float4){a8[0], a8[1], a8[2], a8[3]};
    *reinterpret_cast<float4*>(&sacc[wave * 512 + lane * 8 + 4]) = (float4){a8[4], a8[5], a8[6], a8[7]};
    __syncthreads();
    #pragma unroll
    for (int c = tid; c < CD; c += 256)
        numP[(size_t)pidx * CD + c] =
            sacc[c] + sacc[512 + c] + sacc[1024 + c] + sacc[1536 + c];
}

// ---------------- K2: combine 32 partials -> vbar; out = vbar@Wi + vQp ----------------
__global__ __launch_bounds__(256) void finalize_kernel(
        const float* __restrict__ numP, const float* __restrict__ Zp,
        const float* __restrict__ mP, const float* __restrict__ Wi,
        const float* __restrict__ vQp, float* __restrict__ out)
{
    const int b = blockIdx.x, tid = threadIdx.x;
    __shared__ float sv[CD];
    float M = -1e30f;
    #pragma unroll
    for (int j = 0; j < 32; ++j) M = fmaxf(M, mP[b * 32 + j]);
    float w[32]; float Zt = 0.f;
    #pragma unroll
    for (int j = 0; j < 32; ++j) {
        w[j] = __expf(mP[b * 32 + j] - M);
        Zt += w[j] * Zp[b * 32 + j];
    }
    const float inv = 1.f / Zt;
    for (int c = tid; c < CD; c += 256) {
        float s = 0.f;
        #pragma unroll
        for (int j = 0; j < 32; ++j) s += w[j] * numP[(size_t)(b * 32 + j) * CD + c];
        sv[c] = s * inv;
    }
    __syncthreads();
    float acc = vQp[b * CK + tid];
    #pragma unroll 8
    for (int d = 0; d < CD; ++d) acc += sv[d] * Wi[d * CK + tid];
    out[b * CK + tid] = acc;
}

extern "C" void kernel_launch(void* const* d_in, const int* in_sizes, int n_in,
                              void* d_out, int out_size, void* d_ws, size_t ws_size,
                              hipStream_t stream)
{
    const float* vI = (const float*)d_in[0];   // [B,N,D]
    const float* vQ = (const float*)d_in[1];   // [B,D]
    const float* Wi = (const float*)d_in[2];   // [D,K]
    const float* Wq = (const float*)d_in[3];   // [D,K]
    const float* bq = (const float*)d_in[4];   // [K]
    const float* Wp = (const float*)d_in[5];   // [K,1]
    // d_in[6] = bp: softmax-invariant, unused
    float* out = (float*)d_out;                // [B,K]

    char* ws = (char*)d_ws;
    float*          vQp  = (float*)(ws);                         //  32 KB
    unsigned short* WiT  = (unsigned short*)(ws + 32768);        // 256 KB
    float*          numP = (float*)(ws + 294912);                //   2 MB (1024x512)
    float*          Zp   = (float*)(ws + 294912 + 2097152);      //   4 KB
    float*          mP   = (float*)(ws + 294912 + 2097152 + 4096);

    prep_kernel        <<<CB + CK, 256, 0, stream>>>(vQ, Wq, bq, Wi, vQp, WiT);
    scores_fused_kernel<<<dim3(CN / 64, CB), 256, 0, stream>>>(vI, WiT, vQp, Wp,
                                                               numP, Zp, mP);
    finalize_kernel    <<<CB, 256, 0, stream>>>(numP, Zp, mP, Wi, vQp, out);
}